// Round 4
// baseline (513.255 us; speedup 1.0000x reference)
//
#include <hip/hip_runtime.h>

// MPLayer: out[i,m] = (1/K) sum_{j,l,n} edges[i,j,n] * nodes[nlist[i,j],l] * w[l,m,n]
// N=50000, K=32, F=128, E=16. Two-phase MFMA (fp16 in, fp32 acc).
// v4: phase-1 gather rebuilt around __builtin_amdgcn_global_load_lds:
//   - per-lane scattered dword gather lands DIRECTLY in dword-transposed LDS
//     layout [dwordcol][j] -> A-frags are 2x ds_read_b128 + 4x v_perm
//     (replaces 8x ds_read_u16 + packs; ~3x less DS-pipe time)
//   - double-buffered (s_Ga/s_Gb, parity = r&1 compile-time), depth-2 pipeline,
//     explicit s_waitcnt vmcnt(4); no data VGPRs -> scheduler can't defeat it
//   - 8 chunks x 16 cols: LDS 25KB -> 6 blocks/CU

typedef _Float16 half8  __attribute__((ext_vector_type(8)));
typedef _Float16 half4v __attribute__((ext_vector_type(4)));
typedef float    float4v __attribute__((ext_vector_type(4)));
typedef int      int4v  __attribute__((ext_vector_type(4)));
typedef unsigned int uint;

#define NF 128
#define NK 32
#define NE 16
#define RPB 32

__device__ __forceinline__ void load_lds4(const void* g, void* l) {
    __builtin_amdgcn_global_load_lds((const __attribute__((address_space(1))) void*)g,
                                     (__attribute__((address_space(3))) void*)l, 4, 0, 0);
}

__global__ __launch_bounds__(256) void k_prep_nodes(const float* __restrict__ src,
                                                    _Float16* __restrict__ dst, int n4) {
    int i = blockIdx.x * 256 + threadIdx.x;
    if (i < n4) {
        float4v v = ((const float4v*)src)[i];
        half4v h;
        h[0] = (_Float16)v[0]; h[1] = (_Float16)v[1];
        h[2] = (_Float16)v[2]; h[3] = (_Float16)v[3];
        ((half4v*)dst)[i] = h;
    }
}

// W2t permuted to match phase-1 T store order (8 chunks of 256 c'):
// o = m*2048 + ch*256 + q*64 + n*4 + g  <->  w[l = ch*16 + q*4 + g][m][n]
__global__ __launch_bounds__(256) void k_prep_w(const float* __restrict__ w,
                                                _Float16* __restrict__ w2t) {
    int o  = blockIdx.x * 256 + threadIdx.x;   // 262144 total, exact grid
    int m  = o >> 11;
    int cf = o & 2047;
    int ch = cf >> 8;
    int cp = cf & 255;
    int q  = cp >> 6;
    int n  = (cp >> 2) & 15;
    int g  = cp & 3;
    int l  = ch * 16 + q * 4 + g;
    w2t[o] = (_Float16)w[(l * NF + m) * NE + n];
}

// MFMA 16x16x32 f16 layouts (verified by v1-v3 passing):
//   A: lane holds A[m = lane&15][k = (lane>>4)*8 + jj]
//   B: lane holds B[k = (lane>>4)*8 + jj][n = lane&15]
//   C/D: lane holds D[row = (lane>>4)*4 + g][col = lane&15]
__global__ __launch_bounds__(256, 5) void k_mp(const _Float16* __restrict__ nodes_h,
                                               const int* __restrict__ nlist,
                                               const float* __restrict__ edges,
                                               const _Float16* __restrict__ w2t,
                                               float* __restrict__ out, int N) {
    // s_T: 32 i-rows x 256 c'-halves per chunk (16KB), XOR-swizzled 16B blocks.
    // s_Ga/s_Gb: per-wave gather staging, 4 groups x (64 dwords + 4 pad) = 272
    //   dwords per wave (group pads decollide the 128B-stride b128 reads a bit).
    //   Layout: slot(c,j) = (c>>1)*68 + (c&1)*32 + j  (c = dwordcol 0..7, j = 0..31)
    __shared__ __align__(16) _Float16 s_T[RPB * 256];
    __shared__ __align__(16) uint s_Ga[4 * 272];
    __shared__ __align__(16) uint s_Gb[4 * 272];

    const int tid  = threadIdx.x;
    const int wv   = tid >> 6;
    const int ln   = tid & 63;
    const int quad = ln >> 4;
    const int c16  = ln & 15;
    const int row0 = blockIdx.x * RPB;

    uint* __restrict__ gAw = &s_Ga[wv * 272];
    uint* __restrict__ gBw = &s_Gb[wv * 272];
    const float4v zf = {0.f, 0.f, 0.f, 0.f};

    // ---- edge B-fragments (persistent, 32 VGPRs) ----
    half8 fe[8];
    #pragma unroll
    for (int r = 0; r < 8; ++r) {
        int rg = row0 + wv * 8 + r; if (rg > N - 1) rg = N - 1;
        const float* ep = edges + (size_t)rg * (NK * NE) + quad * (8 * NE) + c16;
        #pragma unroll
        for (int jj = 0; jj < 8; ++jj) fe[r][jj] = (_Float16)ep[jj * NE];
    }

    // ---- neighbor row byte offsets: lane owns j = ln&31 ----
    int nbj[8];
    #pragma unroll
    for (int r = 0; r < 8; ++r) {
        int rg = row0 + wv * 8 + r; if (rg > N - 1) rg = N - 1;
        nbj[r] = nlist[rg * NK + (ln & 31)] << 8;   // *256 bytes per fp16 node row
    }
    // per-lane source base: instr p reads dword (c = 2p + (ln>>5)) of its row
    const char* gsrc = (const char*)nodes_h + ((ln >> 5) << 2);

    float4v a00 = zf, a01 = zf, a10 = zf, a11 = zf;
    const uint psel = 0x05040100u + (uint)(c16 & 1) * 0x02020202u;

    // ---- prologue: stage t=0 -> bufA, t=1 -> bufB ----
    {
        const char* sp0 = gsrc + nbj[0];
        const char* sp1 = gsrc + nbj[1];
        #pragma unroll
        for (int p = 0; p < 4; ++p) load_lds4(sp0 + p * 8, gAw + p * 68);
        #pragma unroll
        for (int p = 0; p < 4; ++p) load_lds4(sp1 + p * 8, gBw + p * 68);
    }

    for (int ch = 0; ch < 8; ++ch) {
        // ================= phase 1 =================
        #pragma unroll
        for (int r = 0; r < 8; ++r) {
            const int il = wv * 8 + r;
            uint* cw = (r & 1) ? gBw : gAw;          // compile-time buffer parity
            // drain this iteration's 4 staging loads (leave next iter's 4 in flight)
            __builtin_amdgcn_s_waitcnt(0x0F74);      // vmcnt(4)
            const int ro = (c16 >> 2) * 68 + ((c16 >> 1) & 1) * 32 + quad * 8;
            uint4 lo = *(const uint4*)(cw + ro);
            uint4 hi = *(const uint4*)(cw + ro + 4);
            uint a0v = __builtin_amdgcn_perm(lo.y, lo.x, psel);
            uint a1v = __builtin_amdgcn_perm(lo.w, lo.z, psel);
            uint a2v = __builtin_amdgcn_perm(hi.y, hi.x, psel);
            uint a3v = __builtin_amdgcn_perm(hi.w, hi.z, psel);
            int4v pv; pv[0] = (int)a0v; pv[1] = (int)a1v; pv[2] = (int)a2v; pv[3] = (int)a3v;
            half8 av = __builtin_bit_cast(half8, pv);
            // refill same-parity buffer for t+2 (issued after reads -> no WAR)
            if (ch * 8 + r < 62) {
                const int r2  = (r + 2) & 7;
                const int ch2 = ch + ((r + 2) >> 3);
                const char* sp = gsrc + nbj[r2] + ch2 * 32;
                #pragma unroll
                for (int p = 0; p < 4; ++p) load_lds4(sp + p * 8, cw + p * 68);
            }
            float4v d = __builtin_amdgcn_mfma_f32_16x16x32_f16(av, fe[r], zf, 0, 0, 0);
            // T store: c' = quad*64 + c16*4 + g, XOR-swizzle 16B blocks by row
            const int cb   = (quad << 6) + (c16 << 2);
            const int phys = cb ^ ((((cb >> 6) ^ il) & 7) << 3);
            half4v hv;
            hv[0] = (_Float16)d[0]; hv[1] = (_Float16)d[1];
            hv[2] = (_Float16)d[2]; hv[3] = (_Float16)d[3];
            *(half4v*)&s_T[il * 256 + phys] = hv;
        }
        __syncthreads();

        // ================= phase 2 =================
        const _Float16* wr0 = w2t + ((size_t)((wv * 2 + 0) * 16 + c16)) * 2048 + ch * 256;
        const _Float16* wr1 = w2t + ((size_t)((wv * 2 + 1) * 16 + c16)) * 2048 + ch * 256;
        #pragma unroll
        for (int kt = 0; kt < 8; ++kt) {
            const int cb2  = (kt << 5) + (quad << 3);
            const int mask = (((cb2 >> 6) ^ c16) & 7) << 3;   // (16+c16)&7 == c16&7
            half8 t0 = *(const half8*)&s_T[c16 * 256        + (cb2 ^ mask)];
            half8 t1 = *(const half8*)&s_T[(16 + c16) * 256 + (cb2 ^ mask)];
            half8 b0 = *(const half8*)(wr0 + cb2);
            half8 b1 = *(const half8*)(wr1 + cb2);
            a00 = __builtin_amdgcn_mfma_f32_16x16x32_f16(t0, b0, a00, 0, 0, 0);
            a10 = __builtin_amdgcn_mfma_f32_16x16x32_f16(t1, b0, a10, 0, 0, 0);
            a01 = __builtin_amdgcn_mfma_f32_16x16x32_f16(t0, b1, a01, 0, 0, 0);
            a11 = __builtin_amdgcn_mfma_f32_16x16x32_f16(t1, b1, a11, 0, 0, 0);
        }
        __syncthreads();   // before next chunk's phase 1 overwrites s_T
    }

    // ---- epilogue: D[row = quad*4+g][col = c16], scale by 1/K ----
    const float sc = 1.0f / (float)NK;
    const int mb = (wv << 5) + c16;
    #pragma unroll
    for (int g = 0; g < 4; ++g) {
        int i0 = row0 + (quad << 2) + g;
        int i1 = i0 + 16;
        if (i0 < N) {
            out[(size_t)i0 * NF + mb]      = a00[g] * sc;
            out[(size_t)i0 * NF + mb + 16] = a01[g] * sc;
        }
        if (i1 < N) {
            out[(size_t)i1 * NF + mb]      = a10[g] * sc;
            out[(size_t)i1 * NF + mb + 16] = a11[g] * sc;
        }
    }
}

extern "C" void kernel_launch(void* const* d_in, const int* in_sizes, int n_in,
                              void* d_out, int out_size, void* d_ws, size_t ws_size,
                              hipStream_t stream) {
    const float* nodes = (const float*)d_in[0];
    const int*   nlist = (const int*)d_in[1];
    const float* edges = (const float*)d_in[2];
    const float* w     = (const float*)d_in[3];
    float* out = (float*)d_out;

    const int N = in_sizes[0] / NF;   // 50000

    _Float16* w2t     = (_Float16*)d_ws;                       // 512KB
    _Float16* nodes_h = (_Float16*)((char*)d_ws + 524288);     // 12.8MB

    const int n4 = (N * NF) / 4;
    k_prep_nodes<<<(n4 + 255) / 256, 256, 0, stream>>>(nodes, nodes_h, n4);
    k_prep_w<<<(NF * NF * NE) / 256, 256, 0, stream>>>(w, w2t);

    const int blocks = (N + RPB - 1) / RPB;                    // 1563
    k_mp<<<blocks, 256, 0, stream>>>(nodes_h, nlist, edges, w2t, out, N);
}

// Round 5
// 431.587 us; speedup vs baseline: 1.1892x; 1.1892x over previous
//
#include <hip/hip_runtime.h>

// MPLayer: out[i,m] = (1/K) sum_{j,l,n} edges[i,j,n] * nodes[nlist[i,j],l] * w[l,m,n]
// N=50000, K=32, F=128, E=16. Two-phase MFMA (fp16 in, fp32 acc).
// v5: producer/consumer wave specialization.
//   - 12-wave block (768 thr): waves 0-7 produce T (gather + phase-1 MFMA) into
//     double-buffered s_T; waves 8-11 consume previous chunk (phase-2 GEMM).
//     Gather latency overlaps consumer MFMA by construction.
//   - gather = direct scattered dword loads + v_perm pack (v4-verified perms,
//     register path) -> NO LDS transpose, DS pipe freed.
//   - chunk = 32 cols (4 passes, 64B/row/pass: v2's L2-friendly granularity).
//   - RPB=16: 3125 blocks exactly, no tail guards.

typedef _Float16 half8  __attribute__((ext_vector_type(8)));
typedef _Float16 half4v __attribute__((ext_vector_type(4)));
typedef float    float4v __attribute__((ext_vector_type(4)));
typedef int      int4v  __attribute__((ext_vector_type(4)));
typedef unsigned int uint;

#define NF 128
#define NK 32
#define NE 16
#define RPB 16

// ---- fused prep: blocks [0,1024) build W2t, blocks [1024,..) convert nodes ----
// W2t permuted (v2-verified): o = m*2048 + ch*512 + ltq*64 + n*4 + g
//   <-> w[l = ch*32 + (ltq>>2)*16 + (ltq&3)*4 + g][m][n]
__global__ __launch_bounds__(256) void k_prep(const float* __restrict__ nodes,
                                              const float* __restrict__ w,
                                              _Float16* __restrict__ nodes_h,
                                              _Float16* __restrict__ w2t, int n4) {
    const int b = blockIdx.x;
    if (b < 1024) {
        int o  = b * 256 + threadIdx.x;      // 262144 exact
        int m  = o >> 11;
        int cf = o & 2047;
        int ch = cf >> 9;
        int cp = cf & 511;
        int ltq = cp >> 6;
        int n   = (cp >> 2) & 15;
        int g   = cp & 3;
        int l = ch * 32 + (ltq >> 2) * 16 + (ltq & 3) * 4 + g;
        w2t[o] = (_Float16)w[(l * NF + m) * NE + n];
    } else {
        int i = (b - 1024) * 256 + threadIdx.x;
        if (i < n4) {
            float4v v = ((const float4v*)nodes)[i];
            half4v h;
            h[0] = (_Float16)v[0]; h[1] = (_Float16)v[1];
            h[2] = (_Float16)v[2]; h[3] = (_Float16)v[3];
            ((half4v*)nodes_h)[i] = h;
        }
    }
}

// MFMA 16x16x32 f16 layouts (verified v1-v4):
//   A: lane holds A[m = lane&15][k = (lane>>4)*8 + jj]
//   B: lane holds B[k = (lane>>4)*8 + jj][n = lane&15]
//   C/D: lane holds D[row = (lane>>4)*4 + g][col = lane&15]
__global__ __launch_bounds__(768, 6) void k_mp(const _Float16* __restrict__ nodes_h,
                                               const int* __restrict__ nlist,
                                               const float* __restrict__ edges,
                                               const _Float16* __restrict__ w2t,
                                               float* __restrict__ out, int N) {
    // double-buffered T: [buf][i-row 0..15][512 permuted-c halves], v2 swizzle
    __shared__ __align__(16) _Float16 s_T[2][RPB * 512];

    const int tid  = threadIdx.x;
    const int wv   = tid >> 6;
    const int ln   = tid & 63;
    const int quad = ln >> 4;
    const int c16  = ln & 15;
    const int row0 = blockIdx.x * RPB;
    const float4v zf = {0.f, 0.f, 0.f, 0.f};

    if (wv < 8) {
        // ======================= PRODUCER =======================
        const int p = wv;                    // owns i-rows p*2, p*2+1
        half8 fe[2];
        int vb[2][8];
        #pragma unroll
        for (int r = 0; r < 2; ++r) {
            const int rg = row0 + p * 2 + r;
            const float* ep = edges + (size_t)rg * (NK * NE) + quad * (8 * NE) + c16;
            #pragma unroll
            for (int jj = 0; jj < 8; ++jj) fe[r][jj] = (_Float16)ep[jj * NE];
            #pragma unroll
            for (int jj = 0; jj < 8; ++jj)
                vb[r][jj] = nlist[rg * NK + quad * 8 + jj] << 8;   // 256B fp16 rows
        }
        const char* gb = (const char*)nodes_h + ((c16 >> 1) << 2);
        const uint psel = 0x05040100u + (uint)(c16 & 1) * 0x02020202u;

        // depth-2 register pipeline over 8 batches t = ch*2 + r
        uint dwA[16], dwB[16];
        #pragma unroll
        for (int q = 0; q < 16; ++q)   // prologue: batch 0 (ch=0, r=0)
            dwA[q] = *(const uint*)(gb + vb[0][q & 7] + ((q >> 3) << 5));

        #pragma unroll
        for (int ch = 0; ch < 4; ++ch) {
            #pragma unroll
            for (int r = 0; r < 2; ++r) {
                const int t = ch * 2 + r;
                uint* cur = (t & 1) ? dwB : dwA;
                uint* nxt = (t & 1) ? dwA : dwB;
                if (t < 7) {               // prefetch batch t+1
                    const int t1 = t + 1, ch1 = t1 >> 1, r1 = t1 & 1;
                    #pragma unroll
                    for (int q = 0; q < 16; ++q)
                        nxt[q] = *(const uint*)(gb + vb[r1][q & 7] + (ch1 << 6) + ((q >> 3) << 5));
                }
                __builtin_amdgcn_sched_barrier(0);   // keep prefetch issued above consume
                const int il = p * 2 + r;
                #pragma unroll
                for (int lt = 0; lt < 2; ++lt) {
                    int4v pv;
                    pv[0] = (int)__builtin_amdgcn_perm(cur[lt*8+1], cur[lt*8+0], psel);
                    pv[1] = (int)__builtin_amdgcn_perm(cur[lt*8+3], cur[lt*8+2], psel);
                    pv[2] = (int)__builtin_amdgcn_perm(cur[lt*8+5], cur[lt*8+4], psel);
                    pv[3] = (int)__builtin_amdgcn_perm(cur[lt*8+7], cur[lt*8+6], psel);
                    half8 av = __builtin_bit_cast(half8, pv);
                    float4v d = __builtin_amdgcn_mfma_f32_16x16x32_f16(av, fe[r], zf, 0, 0, 0);
                    const int ltq  = lt * 4 + quad;
                    const int cb   = ltq * 64 + c16 * 4;
                    const int phys = cb ^ ((((ltq ^ il) & 7)) << 3);
                    half4v hv;
                    hv[0] = (_Float16)d[0]; hv[1] = (_Float16)d[1];
                    hv[2] = (_Float16)d[2]; hv[3] = (_Float16)d[3];
                    *(half4v*)&s_T[ch & 1][il * 512 + phys] = hv;
                }
            }
            __syncthreads();   // publish chunk ch
        }
        // producers exit; consumers have no further barriers
    } else {
        // ======================= CONSUMER =======================
        const int cw = wv - 8;               // owns mtiles 2cw, 2cw+1
        float4v a00 = zf, a01 = zf;
        const _Float16* wr0 = w2t + ((size_t)((cw * 2 + 0) * 16 + c16)) * 2048;
        const _Float16* wr1 = w2t + ((size_t)((cw * 2 + 1) * 16 + c16)) * 2048;

#define CONSUME_CHUNK(cc)                                                          \
        {                                                                          \
            const _Float16* w0 = wr0 + (cc) * 512;                                 \
            const _Float16* w1 = wr1 + (cc) * 512;                                 \
            _Pragma("unroll")                                                      \
            for (int kt = 0; kt < 16; ++kt) {                                      \
                const int cb2  = kt * 32 + quad * 8;                               \
                const int mask = (((cb2 >> 6) ^ c16) & 7) << 3;                    \
                half8 t0 = *(const half8*)&s_T[(cc) & 1][c16 * 512 + (cb2 ^ mask)];\
                half8 b0 = *(const half8*)(w0 + cb2);                              \
                half8 b1 = *(const half8*)(w1 + cb2);                              \
                a00 = __builtin_amdgcn_mfma_f32_16x16x32_f16(t0, b0, a00, 0, 0, 0);\
                a01 = __builtin_amdgcn_mfma_f32_16x16x32_f16(t0, b1, a01, 0, 0, 0);\
            }                                                                      \
        }

        #pragma unroll
        for (int ch = 0; ch < 4; ++ch) {
            if (ch > 0) CONSUME_CHUNK(ch - 1);
            __syncthreads();                 // matches producer barrier count (4)
        }
        CONSUME_CHUNK(3);
#undef CONSUME_CHUNK

        // epilogue: D[row=quad*4+g][col=c16], scale 1/K; N = 16*3125 exact
        const float sc = 1.0f / (float)NK;
        const int mb = cw * 32 + c16;
        #pragma unroll
        for (int g = 0; g < 4; ++g) {
            const int i0 = row0 + quad * 4 + g;
            out[(size_t)i0 * NF + mb]      = a00[g] * sc;
            out[(size_t)i0 * NF + mb + 16] = a01[g] * sc;
        }
    }
}

extern "C" void kernel_launch(void* const* d_in, const int* in_sizes, int n_in,
                              void* d_out, int out_size, void* d_ws, size_t ws_size,
                              hipStream_t stream) {
    const float* nodes = (const float*)d_in[0];
    const int*   nlist = (const int*)d_in[1];
    const float* edges = (const float*)d_in[2];
    const float* w     = (const float*)d_in[3];
    float* out = (float*)d_out;

    const int N = in_sizes[0] / NF;   // 50000

    _Float16* w2t     = (_Float16*)d_ws;                       // 512KB
    _Float16* nodes_h = (_Float16*)((char*)d_ws + 524288);     // 12.8MB

    const int n4 = (N * NF) / 4;                               // 1.6M float4s
    const int prep_blocks = 1024 + (n4 + 255) / 256;           // w2t part + nodes part
    k_prep<<<prep_blocks, 256, 0, stream>>>(nodes, w, nodes_h, w2t, n4);

    const int blocks = N / RPB;                                // 3125 exact
    k_mp<<<blocks, 768, 0, stream>>>(nodes_h, nlist, edges, w2t, out, N);
}

// Round 6
// 403.619 us; speedup vs baseline: 1.2716x; 1.0693x over previous
//
#include <hip/hip_runtime.h>

// MPLayer: out[i,m] = (1/K) sum_{j,l,n} edges[i,j,n] * nodes[nlist[i,j],l] * w[l,m,n]
// N=50000, K=32, F=128, E=16. Two-phase MFMA (fp16 in, fp32 acc).
// v6 = v5 (producer/consumer wave specialization) with the scratch-spill bug
// fixed: v5 selected its double-buffer via `uint* cur = cond ? dwB : dwA`,
// which defeats SROA -> both arrays lived in SCRATCH (VGPR=40, WRITE_SIZE
// 190MB of spill traffic). v6 names the buffers textually via a macro so
// every access is a constant-indexed register after unroll.
//   - 12-wave block (768 thr): waves 0-7 gather + phase-1 MFMA into double-
//     buffered s_T; waves 8-11 run phase-2 GEMM on the previous chunk.
//   - gather = scattered dword loads + v_perm pack (v4/v5-verified), depth-2
//     register pipeline, prefetch issued before consume, sched_barrier pinned.
//   - RPB=16: 3125 blocks exact, no tail guards.

typedef _Float16 half8  __attribute__((ext_vector_type(8)));
typedef _Float16 half4v __attribute__((ext_vector_type(4)));
typedef float    float4v __attribute__((ext_vector_type(4)));
typedef int      int4v  __attribute__((ext_vector_type(4)));
typedef unsigned int uint;

#define NF 128
#define NK 32
#define NE 16
#define RPB 16

// ---- fused prep: blocks [0,1024) build W2t, blocks [1024,..) convert nodes ----
// W2t permuted (v2-verified): o = m*2048 + ch*512 + ltq*64 + n*4 + g
//   <-> w[l = ch*32 + (ltq>>2)*16 + (ltq&3)*4 + g][m][n]
__global__ __launch_bounds__(256) void k_prep(const float* __restrict__ nodes,
                                              const float* __restrict__ w,
                                              _Float16* __restrict__ nodes_h,
                                              _Float16* __restrict__ w2t, int n4) {
    const int b = blockIdx.x;
    if (b < 1024) {
        int o  = b * 256 + threadIdx.x;      // 262144 exact
        int m  = o >> 11;
        int cf = o & 2047;
        int ch = cf >> 9;
        int cp = cf & 511;
        int ltq = cp >> 6;
        int n   = (cp >> 2) & 15;
        int g   = cp & 3;
        int l = ch * 32 + (ltq >> 2) * 16 + (ltq & 3) * 4 + g;
        w2t[o] = (_Float16)w[(l * NF + m) * NE + n];
    } else {
        int i = (b - 1024) * 256 + threadIdx.x;
        if (i < n4) {
            float4v v = ((const float4v*)nodes)[i];
            half4v h;
            h[0] = (_Float16)v[0]; h[1] = (_Float16)v[1];
            h[2] = (_Float16)v[2]; h[3] = (_Float16)v[3];
            ((half4v*)nodes_h)[i] = h;
        }
    }
}

// MFMA 16x16x32 f16 layouts (verified v1-v5):
//   A: lane holds A[m = lane&15][k = (lane>>4)*8 + jj]
//   B: lane holds B[k = (lane>>4)*8 + jj][n = lane&15]
//   C/D: lane holds D[row = (lane>>4)*4 + g][col = lane&15]
__global__ __launch_bounds__(768, 6) void k_mp(const _Float16* __restrict__ nodes_h,
                                               const int* __restrict__ nlist,
                                               const float* __restrict__ edges,
                                               const _Float16* __restrict__ w2t,
                                               float* __restrict__ out, int N) {
    // double-buffered T: [buf][i-row 0..15][512 permuted-c halves], v2 swizzle
    __shared__ __align__(16) _Float16 s_T[2][RPB * 512];

    const int tid  = threadIdx.x;
    const int wv   = tid >> 6;
    const int ln   = tid & 63;
    const int quad = ln >> 4;
    const int c16  = ln & 15;
    const int row0 = blockIdx.x * RPB;
    const float4v zf = {0.f, 0.f, 0.f, 0.f};

    if (wv < 8) {
        // ======================= PRODUCER =======================
        const int p = wv;                    // owns i-rows p*2, p*2+1
        half8 fe[2];
        int vb[2][8];
        #pragma unroll
        for (int r = 0; r < 2; ++r) {
            const int rg = row0 + p * 2 + r;
            const float* ep = edges + (size_t)rg * (NK * NE) + quad * (8 * NE) + c16;
            #pragma unroll
            for (int jj = 0; jj < 8; ++jj) fe[r][jj] = (_Float16)ep[jj * NE];
            #pragma unroll
            for (int jj = 0; jj < 8; ++jj)
                vb[r][jj] = nlist[rg * NK + quad * 8 + jj] << 8;   // 256B fp16 rows
        }
        const char* gb = (const char*)nodes_h + ((c16 >> 1) << 2);
        const uint psel = 0x05040100u + (uint)(c16 & 1) * 0x02020202u;

        // depth-2 register pipeline over 8 batches t = ch*2 + r.
        // CUR/NXT are ARRAY NAMES (textual macro) -> SROA keeps them in VGPRs.
        uint dwA[16], dwB[16];
        #pragma unroll
        for (int q = 0; q < 16; ++q)   // prologue: batch 0 (ch=0, r=0)
            dwA[q] = *(const uint*)(gb + vb[0][q & 7] + ((q >> 3) << 5));

#define PROD_BATCH(CUR, NXT, CH, R)                                               \
        {                                                                         \
            const int t_ = (CH) * 2 + (R);                                        \
            if (t_ < 7) {              /* prefetch batch t+1 */                   \
                const int t1_ = t_ + 1, ch1_ = t1_ >> 1, r1_ = t1_ & 1;           \
                _Pragma("unroll")                                                 \
                for (int q = 0; q < 16; ++q)                                      \
                    NXT[q] = *(const uint*)(gb + vb[r1_][q & 7] + (ch1_ << 6)     \
                                            + ((q >> 3) << 5));                   \
            }                                                                     \
            __builtin_amdgcn_sched_barrier(0);                                    \
            const int il_ = p * 2 + (R);                                          \
            _Pragma("unroll")                                                     \
            for (int lt = 0; lt < 2; ++lt) {                                      \
                int4v pv;                                                         \
                pv[0] = (int)__builtin_amdgcn_perm(CUR[lt*8+1], CUR[lt*8+0], psel);\
                pv[1] = (int)__builtin_amdgcn_perm(CUR[lt*8+3], CUR[lt*8+2], psel);\
                pv[2] = (int)__builtin_amdgcn_perm(CUR[lt*8+5], CUR[lt*8+4], psel);\
                pv[3] = (int)__builtin_amdgcn_perm(CUR[lt*8+7], CUR[lt*8+6], psel);\
                half8 av = __builtin_bit_cast(half8, pv);                         \
                float4v d = __builtin_amdgcn_mfma_f32_16x16x32_f16(av, fe[R], zf, \
                                                                   0, 0, 0);      \
                const int ltq_  = lt * 4 + quad;                                  \
                const int cb_   = ltq_ * 64 + c16 * 4;                            \
                const int phys_ = cb_ ^ ((((ltq_ ^ il_) & 7)) << 3);              \
                half4v hv;                                                        \
                hv[0] = (_Float16)d[0]; hv[1] = (_Float16)d[1];                   \
                hv[2] = (_Float16)d[2]; hv[3] = (_Float16)d[3];                   \
                *(half4v*)&s_T[(CH) & 1][il_ * 512 + phys_] = hv;                 \
            }                                                                     \
        }

        #pragma unroll
        for (int ch = 0; ch < 4; ++ch) {
            PROD_BATCH(dwA, dwB, ch, 0)
            PROD_BATCH(dwB, dwA, ch, 1)
            __syncthreads();   // publish chunk ch
        }
#undef PROD_BATCH
        // producers exit; barrier counts matched with consumers (4 each)
    } else {
        // ======================= CONSUMER =======================
        const int cw = wv - 8;               // owns mtiles 2cw, 2cw+1
        float4v a00 = zf, a01 = zf;
        const _Float16* wr0 = w2t + ((size_t)((cw * 2 + 0) * 16 + c16)) * 2048;
        const _Float16* wr1 = w2t + ((size_t)((cw * 2 + 1) * 16 + c16)) * 2048;

#define CONSUME_CHUNK(cc)                                                          \
        {                                                                          \
            const _Float16* w0 = wr0 + (cc) * 512;                                 \
            const _Float16* w1 = wr1 + (cc) * 512;                                 \
            _Pragma("unroll")                                                      \
            for (int kt = 0; kt < 16; ++kt) {                                      \
                const int cb2  = kt * 32 + quad * 8;                               \
                const int mask = (((cb2 >> 6) ^ c16) & 7) << 3;                    \
                half8 t0 = *(const half8*)&s_T[(cc) & 1][c16 * 512 + (cb2 ^ mask)];\
                half8 b0 = *(const half8*)(w0 + cb2);                              \
                half8 b1 = *(const half8*)(w1 + cb2);                              \
                a00 = __builtin_amdgcn_mfma_f32_16x16x32_f16(t0, b0, a00, 0, 0, 0);\
                a01 = __builtin_amdgcn_mfma_f32_16x16x32_f16(t0, b1, a01, 0, 0, 0);\
            }                                                                      \
        }

        #pragma unroll
        for (int ch = 0; ch < 4; ++ch) {
            if (ch > 0) CONSUME_CHUNK(ch - 1);
            __syncthreads();                 // matches producer barrier count (4)
        }
        CONSUME_CHUNK(3);
#undef CONSUME_CHUNK

        // epilogue: D[row=quad*4+g][col=c16], scale 1/K; N = 16*3125 exact
        const float sc = 1.0f / (float)NK;
        const int mb = cw * 32 + c16;
        #pragma unroll
        for (int g = 0; g < 4; ++g) {
            const int i0 = row0 + quad * 4 + g;
            out[(size_t)i0 * NF + mb]      = a00[g] * sc;
            out[(size_t)i0 * NF + mb + 16] = a01[g] * sc;
        }
    }
}

extern "C" void kernel_launch(void* const* d_in, const int* in_sizes, int n_in,
                              void* d_out, int out_size, void* d_ws, size_t ws_size,
                              hipStream_t stream) {
    const float* nodes = (const float*)d_in[0];
    const int*   nlist = (const int*)d_in[1];
    const float* edges = (const float*)d_in[2];
    const float* w     = (const float*)d_in[3];
    float* out = (float*)d_out;

    const int N = in_sizes[0] / NF;   // 50000

    _Float16* w2t     = (_Float16*)d_ws;                       // 512KB
    _Float16* nodes_h = (_Float16*)((char*)d_ws + 524288);     // 12.8MB

    const int n4 = (N * NF) / 4;                               // 1.6M float4s
    const int prep_blocks = 1024 + (n4 + 255) / 256;           // w2t part + nodes part
    k_prep<<<prep_blocks, 256, 0, stream>>>(nodes, w, nodes_h, w2t, n4);

    const int blocks = N / RPB;                                // 3125 exact
    k_mp<<<blocks, 768, 0, stream>>>(nodes_h, nlist, edges, w2t, out, N);
}